// Round 1
// baseline (159.616 us; speedup 1.0000x reference)
//
#include <hip/hip_runtime.h>
#include <hip/hip_bf16.h>
#include <math.h>

typedef __attribute__((ext_vector_type(8))) __bf16 bf16x8;
typedef __attribute__((ext_vector_type(4))) float f32x4;
typedef __attribute__((ext_vector_type(8))) unsigned short u16x8;

__device__ __forceinline__ float sigmoid_f(float v) {
  return __builtin_amdgcn_rcpf(1.f + __expf(-v));
}
__device__ __forceinline__ float tanh_f(float z) {
  float az = fabsf(z);
  float e = __expf(-2.f * az);
  float t = (1.f - e) * __builtin_amdgcn_rcpf(1.f + e);
  return copysignf(t, z);
}
__device__ __forceinline__ bf16x8 cvt8(float4 a, float4 b) {
  bf16x8 r;
  r[0] = (__bf16)a.x; r[1] = (__bf16)a.y; r[2] = (__bf16)a.z; r[3] = (__bf16)a.w;
  r[4] = (__bf16)b.x; r[5] = (__bf16)b.y; r[6] = (__bf16)b.z; r[7] = (__bf16)b.w;
  return r;
}

// Pack W_x/W_h fp32 -> bf16, 6 matrices of 128x128 in MFMA-B-FRAGMENT order:
// within matrix m, 16B chunk c = (nt*4 + kt)*64 + lane  (lane = quad*16 + l15)
// holds W[ro + nt*16 + l15][kt*32 + quad*8 .. +7].
// This makes global_load_lds staging (wave-uniform base + lane*16) land exactly
// where the ds_read_b128 B-frag reads expect it: both are wave-linear 1KB, 0 conflicts.
// matrix order: 0 Wx_r, 1 Wh_r, 2 Wh_h, 3 Wx_h, 4 Wx_u, 5 Wh_u
__global__ void pack_weights_kernel(const float* __restrict__ Wx,
                                    const float* __restrict__ Wh,
                                    unsigned short* __restrict__ wp) {
  int t = blockIdx.x * 256 + threadIdx.x;
  if (t >= 12288) return;          // 6 * 2048 chunks of 8 elems
  int m    = t >> 11;
  int c    = t & 2047;
  int nt   = c >> 8;
  int kt   = (c >> 6) & 3;
  int lane = c & 63;
  const float* src; int ro;
  switch (m) {
    case 0: src = Wx; ro = 128; break;
    case 1: src = Wh; ro = 128; break;
    case 2: src = Wh; ro = 256; break;
    case 3: src = Wx; ro = 256; break;
    case 4: src = Wx; ro = 0;   break;
    default: src = Wh; ro = 0;  break;
  }
  const float* p = src + (ro + nt * 16 + (lane & 15)) * 128 + kt * 32 + (lane >> 4) * 8;
  float4 a = *(const float4*)p;
  float4 b = *(const float4*)(p + 4);
  *(bf16x8*)(wp + m * 16384 + c * 8) = cvt8(a, b);
}

__global__ __launch_bounds__(256, 2) void augru_kernel(
    const float* __restrict__ x, const float* __restrict__ hp,
    const float* __restrict__ att, const unsigned short* __restrict__ wp,
    const float* __restrict__ bx, const float* __restrict__ bh,
    float* __restrict__ out) {
  // double-buffered weight LDS: 2 x 32KB, linear fragment order, no padding needed
  __shared__ __align__(16) unsigned short wlds[2][16384];
  const int tid  = threadIdx.x;
  const int wave = tid >> 6;
  const int lane = tid & 63;
  const int quad = lane >> 4;
  const int l15  = lane & 15;
  const int rw   = blockIdx.x * 128 + wave * 32;  // this wave's 32-row chunk (2 M-tiles)

  // async stage of one 32KB matrix into LDS buffer b: 8 rounds x 4 waves x 1KB
  auto stage = [&](int m, int b) {
#pragma unroll
    for (int i = 0; i < 8; ++i) {
      const unsigned short* g = wp + m * 16384 + ((i * 4 + wave) * 64 + lane) * 8;
      unsigned short* l = &wlds[b][(i * 4 + wave) * 512];  // wave-uniform base; HW adds lane*16
#if __has_builtin(__builtin_amdgcn_global_load_lds)
      __builtin_amdgcn_global_load_lds(
          (const __attribute__((address_space(1))) void*)g,
          (__attribute__((address_space(3))) void*)l, 16, 0, 0);
#else
      *(u16x8*)(l + lane * 8) = *(const u16x8*)g;
#endif
    }
  };

  stage(0, 0);  // Wx_r -> buf0, in flight while we load A-fragments

  // A fragments straight from global fp32 -> bf16 regs. A[m=l15][k=quad*8+j].
  bf16x8 xf[2][4], hf[2][4];
#pragma unroll
  for (int rt = 0; rt < 2; ++rt) {
    const float* xr = x  + (rw + rt * 16 + l15) * 128;
    const float* hr = hp + (rw + rt * 16 + l15) * 128;
#pragma unroll
    for (int kt = 0; kt < 4; ++kt) {
      int off = kt * 32 + quad * 8;
      xf[rt][kt] = cvt8(*(const float4*)(xr + off), *(const float4*)(xr + off + 4));
      hf[rt][kt] = cvt8(*(const float4*)(hr + off), *(const float4*)(hr + off + 4));
    }
  }

  f32x4 acc[2][8], keep[2][8];
#pragma unroll
  for (int rt = 0; rt < 2; ++rt)
#pragma unroll
    for (int nt = 0; nt < 8; ++nt) acc[rt][nt] = (f32x4)0.f;

  // one B-frag ds_read feeds 2 MFMAs (both row-tiles) -> MFMA-bound inner loop
  auto gemm = [&](int b, const bf16x8 (&af)[2][4]) {
#pragma unroll
    for (int nt = 0; nt < 8; ++nt) {
#pragma unroll
      for (int kt = 0; kt < 4; ++kt) {
        bf16x8 bfrag = *(const bf16x8*)&wlds[b][((nt * 4 + kt) * 64 + lane) * 8];
        acc[0][nt] = __builtin_amdgcn_mfma_f32_16x16x32_bf16(af[0][kt], bfrag, acc[0][nt], 0, 0, 0);
        acc[1][nt] = __builtin_amdgcn_mfma_f32_16x16x32_bf16(af[1][kt], bfrag, acc[1][nt], 0, 0, 0);
      }
    }
  };
  // drain own global_load_lds, then join: after this, the staged buffer is complete
  auto barrier = [&]() {
    asm volatile("s_waitcnt vmcnt(0)" ::: "memory");
    __syncthreads();
  };

  barrier();  // pass-0 weights resident

  // pass 0: x.Wx_r            (read buf0, prefetch Wh_r -> buf1)
  stage(1, 1); gemm(0, xf); barrier();
  // pass 1: + h.Wh_r -> r     (read buf1, prefetch Wh_h -> buf0)
  stage(2, 0); gemm(1, hf);
#pragma unroll
  for (int nt = 0; nt < 8; ++nt) {
    int col = nt * 16 + l15;
    float br = bx[128 + col] + bh[128 + col];
#pragma unroll
    for (int rt = 0; rt < 2; ++rt)
#pragma unroll
      for (int r = 0; r < 4; ++r) {
        keep[rt][nt][r] = sigmoid_f(acc[rt][nt][r] + br);
        acc[rt][nt][r] = 0.f;
      }
  }
  barrier();
  // pass 2: h.Wh_h -> t = r * (g + bh_h)
  stage(3, 1); gemm(0, hf);
#pragma unroll
  for (int nt = 0; nt < 8; ++nt) {
    int col = nt * 16 + l15;
    float bhh = bh[256 + col];
#pragma unroll
    for (int rt = 0; rt < 2; ++rt)
#pragma unroll
      for (int r = 0; r < 4; ++r) {
        keep[rt][nt][r] = keep[rt][nt][r] * (acc[rt][nt][r] + bhh);
        acc[rt][nt][r] = 0.f;
      }
  }
  barrier();
  // pass 3: x.Wx_h -> h_tilde = tanh(g + bx_h + t)
  stage(4, 0); gemm(1, xf);
#pragma unroll
  for (int nt = 0; nt < 8; ++nt) {
    int col = nt * 16 + l15;
    float bxh = bx[256 + col];
#pragma unroll
    for (int rt = 0; rt < 2; ++rt)
#pragma unroll
      for (int r = 0; r < 4; ++r) {
        keep[rt][nt][r] = tanh_f(acc[rt][nt][r] + bxh + keep[rt][nt][r]);
        acc[rt][nt][r] = 0.f;
      }
  }
  barrier();
  // pass 4: x.Wx_u            (prefetch Wh_u -> buf1)
  stage(5, 1); gemm(0, xf); barrier();
  // pass 5: + h.Wh_u -> u, blend, store
  gemm(1, hf);

  float atts[2][4];
#pragma unroll
  for (int rt = 0; rt < 2; ++rt)
#pragma unroll
    for (int r = 0; r < 4; ++r) atts[rt][r] = att[rw + rt * 16 + quad * 4 + r];
#pragma unroll
  for (int nt = 0; nt < 8; ++nt) {
    int col = nt * 16 + l15;
    float bu = bx[col] + bh[col];
#pragma unroll
    for (int rt = 0; rt < 2; ++rt)
#pragma unroll
      for (int r = 0; r < 4; ++r) {
        int row = rw + rt * 16 + quad * 4 + r;
        float u  = sigmoid_f(acc[rt][nt][r] + bu);
        float ua = atts[rt][r] * u;
        float h0 = hp[row * 128 + col];
        out[row * 128 + col] = fmaf(ua, keep[rt][nt][r] - h0, h0);  // (1-ua)*h0 + ua*ht
      }
  }
}

extern "C" void kernel_launch(void* const* d_in, const int* in_sizes, int n_in,
                              void* d_out, int out_size, void* d_ws, size_t ws_size,
                              hipStream_t stream) {
  const float* x   = (const float*)d_in[0];
  const float* hpv = (const float*)d_in[1];
  const float* att = (const float*)d_in[2];
  const float* Wx  = (const float*)d_in[3];
  const float* bx  = (const float*)d_in[4];
  const float* Wh  = (const float*)d_in[5];
  const float* bh  = (const float*)d_in[6];
  float* out = (float*)d_out;
  unsigned short* wp = (unsigned short*)d_ws;  // 196,608 B of scratch

  pack_weights_kernel<<<48, 256, 0, stream>>>(Wx, Wh, wp);
  augru_kernel<<<512, 256, 0, stream>>>(x, hpv, att, wp, bx, bh, out);
}

// Round 2
// 133.247 us; speedup vs baseline: 1.1979x; 1.1979x over previous
//
#include <hip/hip_runtime.h>
#include <hip/hip_bf16.h>
#include <math.h>

typedef __attribute__((ext_vector_type(8))) __bf16 bf16x8;
typedef __attribute__((ext_vector_type(4))) float f32x4;
typedef __attribute__((ext_vector_type(8))) unsigned short u16x8;

__device__ __forceinline__ float sigmoid_f(float v) {
  return __builtin_amdgcn_rcpf(1.f + __expf(-v));
}
__device__ __forceinline__ float tanh_f(float z) {
  float az = fabsf(z);
  float e = __expf(-2.f * az);
  float t = (1.f - e) * __builtin_amdgcn_rcpf(1.f + e);
  return copysignf(t, z);
}
__device__ __forceinline__ bf16x8 cvt8(float4 a, float4 b) {
  bf16x8 r;
  r[0] = (__bf16)a.x; r[1] = (__bf16)a.y; r[2] = (__bf16)a.z; r[3] = (__bf16)a.w;
  r[4] = (__bf16)b.x; r[5] = (__bf16)b.y; r[6] = (__bf16)b.z; r[7] = (__bf16)b.w;
  return r;
}

// Pack W_x/W_h fp32 -> bf16 in column-half-major fragment order.
// Linear 16B chunk id t = ch*6144 + m*1024 + c2, c2 = (nt*4+kt)*64 + lane.
// Chunk holds W[ro + ch*64 + nt*16 + (lane&15)][kt*32 + (lane>>4)*8 .. +7].
// So wp[ch] is one contiguous 96KB block: all 6 matrices for that col-half,
// in the exact order global_load_lds staging + ds_read_b128 B-frag reads expect.
// matrix order m: 0 Wx_r, 1 Wh_r, 2 Wh_h, 3 Wx_h, 4 Wx_u, 5 Wh_u
__global__ void pack_weights_kernel(const float* __restrict__ Wx,
                                    const float* __restrict__ Wh,
                                    unsigned short* __restrict__ wp) {
  int t = blockIdx.x * 256 + threadIdx.x;
  if (t >= 12288) return;          // 2 halves * 6 matrices * 1024 chunks
  int ch = t / 6144;
  int r  = t - ch * 6144;
  int m  = r >> 10;
  int c2 = r & 1023;
  int nt = c2 >> 8;
  int kt = (c2 >> 6) & 3;
  int lane = c2 & 63;
  const float* src; int ro;
  switch (m) {
    case 0: src = Wx; ro = 128; break;
    case 1: src = Wh; ro = 128; break;
    case 2: src = Wh; ro = 256; break;
    case 3: src = Wx; ro = 256; break;
    case 4: src = Wx; ro = 0;   break;
    default: src = Wh; ro = 0;  break;
  }
  const float* p = src + (ro + ch * 64 + nt * 16 + (lane & 15)) * 128
                       + kt * 32 + (lane >> 4) * 8;
  *(bf16x8*)(wp + t * 8) = cvt8(*(const float4*)p, *(const float4*)(p + 4));
}

// 512 threads = 8 waves; block owns 256 rows x 128 cols, split into 2 column-phases.
// All 6 weight matrices for one col-half (96KB) resident in LDS per phase ->
// zero barriers inside the 6 gemm passes. 3 barriers per block total.
__global__ __launch_bounds__(512, 2) void augru_kernel(
    const float* __restrict__ x, const float* __restrict__ hp,
    const float* __restrict__ att, const unsigned short* __restrict__ wp,
    const float* __restrict__ bx, const float* __restrict__ bh,
    float* __restrict__ out) {
  extern __shared__ unsigned short wlds[];  // 96KB = 49152 shorts
  const int tid  = threadIdx.x;
  const int wave = tid >> 6;
  const int lane = tid & 63;
  const int quad = lane >> 4;
  const int l15  = lane & 15;
  const int rw   = blockIdx.x * 256 + wave * 32;  // wave's 32 rows

  // stage one col-half's weights (96KB): 12 rounds x 512 lanes x 16B, linear
  auto stage = [&](int ch) {
#pragma unroll
    for (int i = 0; i < 12; ++i) {
      const unsigned short* g = wp + ch * 49152 + (i * 512 + tid) * 8;
      unsigned short* l = &wlds[(i * 512 + wave * 64) * 8];  // wave-uniform; HW adds lane*16
      __builtin_amdgcn_global_load_lds(
          (const __attribute__((address_space(1))) void*)g,
          (__attribute__((address_space(3))) void*)l, 16, 0, 0);
    }
  };

  stage(0);  // in flight while we build A-fragments

  // A-fragments: global fp32 -> bf16 regs, held for the whole kernel.
  // A[m = l15][k = quad*8+j] per 16x16x32 K-tile; rt = row-tile (2 x 16 rows).
  bf16x8 xf[2][4], hf[2][4];
#pragma unroll
  for (int rt = 0; rt < 2; ++rt) {
    const float* xr = x  + (rw + rt * 16 + l15) * 128;
    const float* hr = hp + (rw + rt * 16 + l15) * 128;
#pragma unroll
    for (int kt = 0; kt < 4; ++kt) {
      int off = kt * 32 + quad * 8;
      xf[rt][kt] = cvt8(*(const float4*)(xr + off), *(const float4*)(xr + off + 4));
      hf[rt][kt] = cvt8(*(const float4*)(hr + off), *(const float4*)(hr + off + 4));
    }
  }

  float atts[2][4];
#pragma unroll
  for (int rt = 0; rt < 2; ++rt)
#pragma unroll
    for (int r = 0; r < 4; ++r) atts[rt][r] = att[rw + rt * 16 + quad * 4 + r];

  f32x4 acc[2][4], keep[2][4];

  // one B-frag ds_read feeds 2 MFMAs (both row-tiles)
  auto gemm = [&](int m, const bf16x8 (&af)[2][4]) {
#pragma unroll
    for (int nt = 0; nt < 4; ++nt)
#pragma unroll
      for (int kt = 0; kt < 4; ++kt) {
        bf16x8 bfrag = *(const bf16x8*)&wlds[m * 8192 + ((nt * 4 + kt) * 64 + lane) * 8];
        acc[0][nt] = __builtin_amdgcn_mfma_f32_16x16x32_bf16(af[0][kt], bfrag, acc[0][nt], 0, 0, 0);
        acc[1][nt] = __builtin_amdgcn_mfma_f32_16x16x32_bf16(af[1][kt], bfrag, acc[1][nt], 0, 0, 0);
      }
  };

  // 6 gemm passes for one col-half; leaves acc = u-gates, keep = h_tilde
  auto do_passes = [&](int ch) {
    const int cb = ch * 64;
#pragma unroll
    for (int rt = 0; rt < 2; ++rt)
#pragma unroll
      for (int nt = 0; nt < 4; ++nt) acc[rt][nt] = (f32x4)0.f;
    // pass 0: x.Wx_r ; pass 1: + h.Wh_r -> r
    gemm(0, xf);
    gemm(1, hf);
#pragma unroll
    for (int nt = 0; nt < 4; ++nt) {
      int col = cb + nt * 16 + l15;
      float br = bx[128 + col] + bh[128 + col];
#pragma unroll
      for (int rt = 0; rt < 2; ++rt)
#pragma unroll
        for (int r = 0; r < 4; ++r) {
          keep[rt][nt][r] = sigmoid_f(acc[rt][nt][r] + br);
          acc[rt][nt][r] = 0.f;
        }
    }
    // pass 2: h.Wh_h -> t = r * (g + bh_h)
    gemm(2, hf);
#pragma unroll
    for (int nt = 0; nt < 4; ++nt) {
      int col = cb + nt * 16 + l15;
      float bhh = bh[256 + col];
#pragma unroll
      for (int rt = 0; rt < 2; ++rt)
#pragma unroll
        for (int r = 0; r < 4; ++r) {
          keep[rt][nt][r] = keep[rt][nt][r] * (acc[rt][nt][r] + bhh);
          acc[rt][nt][r] = 0.f;
        }
    }
    // pass 3: x.Wx_h -> h_tilde = tanh(g + bx_h + t)
    gemm(3, xf);
#pragma unroll
    for (int nt = 0; nt < 4; ++nt) {
      int col = cb + nt * 16 + l15;
      float bxh = bx[256 + col];
#pragma unroll
      for (int rt = 0; rt < 2; ++rt)
#pragma unroll
        for (int r = 0; r < 4; ++r) {
          keep[rt][nt][r] = tanh_f(acc[rt][nt][r] + bxh + keep[rt][nt][r]);
          acc[rt][nt][r] = 0.f;
        }
    }
    // pass 4: x.Wx_u ; pass 5: + h.Wh_u
    gemm(4, xf);
    gemm(5, hf);
  };

  auto do_epilogue = [&](int ch) {
    const int cb = ch * 64;
#pragma unroll
    for (int nt = 0; nt < 4; ++nt) {
      int col = cb + nt * 16 + l15;
      float bu = bx[col] + bh[col];
#pragma unroll
      for (int rt = 0; rt < 2; ++rt)
#pragma unroll
        for (int r = 0; r < 4; ++r) {
          int row = rw + rt * 16 + quad * 4 + r;
          float u  = sigmoid_f(acc[rt][nt][r] + bu);
          float ua = atts[rt][r] * u;
          float h0 = hp[row * 128 + col];
          out[row * 128 + col] = fmaf(ua, keep[rt][nt][r] - h0, h0);
        }
    }
  };

  asm volatile("s_waitcnt vmcnt(0)" ::: "memory");
  __syncthreads();           // col-half-0 weights resident

  do_passes(0);
  __syncthreads();           // all waves done reading wlds for phase 0
  stage(1);                  // async re-stage overlaps epilogue VALU
  do_epilogue(0);
  asm volatile("s_waitcnt vmcnt(0)" ::: "memory");
  __syncthreads();           // col-half-1 weights resident

  do_passes(1);
  do_epilogue(1);
}

extern "C" void kernel_launch(void* const* d_in, const int* in_sizes, int n_in,
                              void* d_out, int out_size, void* d_ws, size_t ws_size,
                              hipStream_t stream) {
  const float* x   = (const float*)d_in[0];
  const float* hpv = (const float*)d_in[1];
  const float* att = (const float*)d_in[2];
  const float* Wx  = (const float*)d_in[3];
  const float* bx  = (const float*)d_in[4];
  const float* Wh  = (const float*)d_in[5];
  const float* bh  = (const float*)d_in[6];
  float* out = (float*)d_out;
  unsigned short* wp = (unsigned short*)d_ws;  // 196,608 B of scratch

  pack_weights_kernel<<<48, 256, 0, stream>>>(Wx, Wh, wp);
  augru_kernel<<<256, 512, 98304, stream>>>(x, hpv, att, wp, bx, bh, out);
}

// Round 3
// 125.062 us; speedup vs baseline: 1.2763x; 1.0654x over previous
//
#include <hip/hip_runtime.h>
#include <hip/hip_bf16.h>
#include <math.h>

typedef __attribute__((ext_vector_type(8))) __bf16 bf16x8;
typedef __attribute__((ext_vector_type(4))) float f32x4;
typedef __attribute__((ext_vector_type(8))) unsigned short u16x8;

__device__ __forceinline__ float sigmoid_f(float v) {
  return __builtin_amdgcn_rcpf(1.f + __expf(-v));
}
__device__ __forceinline__ float tanh_f(float z) {
  float az = fabsf(z);
  float e = __expf(-2.f * az);
  float t = (1.f - e) * __builtin_amdgcn_rcpf(1.f + e);
  return copysignf(t, z);
}
__device__ __forceinline__ bf16x8 cvt8(float4 a, float4 b) {
  bf16x8 r;
  r[0] = (__bf16)a.x; r[1] = (__bf16)a.y; r[2] = (__bf16)a.z; r[3] = (__bf16)a.w;
  r[4] = (__bf16)b.x; r[5] = (__bf16)b.y; r[6] = (__bf16)b.z; r[7] = (__bf16)b.w;
  return r;
}

// Pack W_x/W_h fp32 -> bf16 into 12 phase-blocks of 16KB (col-half ch major,
// then pass m). 16B chunk id t = (ch*6 + m)*1024 + c2, c2 = (nt*4+kt)*64 + lane.
// Chunk holds W[ro + ch*64 + nt*16 + (lane&15)][kt*32 + (lane>>4)*8 .. +7].
// global_load_lds staging (wave-uniform base + lane*16) then lands exactly where
// the ds_read_b128 B-frag reads expect it: both wave-linear, 0 bank conflicts.
// pass order m: 0 Wx_r, 1 Wh_r, 2 Wh_h, 3 Wx_h, 4 Wx_u, 5 Wh_u
__global__ void pack_weights_kernel(const float* __restrict__ Wx,
                                    const float* __restrict__ Wh,
                                    unsigned short* __restrict__ wp) {
  int t = blockIdx.x * 256 + threadIdx.x;
  if (t >= 12288) return;          // 2 halves * 6 matrices * 1024 chunks
  int ch = t / 6144;
  int r  = t - ch * 6144;
  int m  = r >> 10;
  int c2 = r & 1023;
  int nt = c2 >> 8;
  int kt = (c2 >> 6) & 3;
  int lane = c2 & 63;
  const float* src; int ro;
  switch (m) {
    case 0: src = Wx; ro = 128; break;
    case 1: src = Wh; ro = 128; break;
    case 2: src = Wh; ro = 256; break;
    case 3: src = Wx; ro = 256; break;
    case 4: src = Wx; ro = 0;   break;
    default: src = Wh; ro = 0;  break;
  }
  const float* p = src + (ro + ch * 64 + nt * 16 + (lane & 15)) * 128
                       + kt * 32 + (lane >> 4) * 8;
  *(bf16x8*)(wp + t * 8) = cvt8(*(const float4*)p, *(const float4*)(p + 4));
}

// 256 threads = 4 waves; wave owns 16 rows. 12 phases of 16KB weights,
// double-buffered in 32KB LDS, 1 barrier per phase. Whole grid co-resident.
__global__ __launch_bounds__(256, 2) void augru_kernel(
    const float* __restrict__ x, const float* __restrict__ hp,
    const float* __restrict__ att, const unsigned short* __restrict__ wp,
    const float* __restrict__ bx, const float* __restrict__ bh,
    float* __restrict__ out) {
  __shared__ __align__(16) unsigned short wlds[2][8192];  // 2 x 16KB
  const int tid  = threadIdx.x;
  const int wave = tid >> 6;
  const int lane = tid & 63;
  const int quad = lane >> 4;
  const int l15  = lane & 15;
  const int rb   = blockIdx.x * 64 + wave * 16;  // this wave's 16 rows

  // stage phase p's 16KB into buf p&1: 4 rounds x 256 threads x 16B, linear
  auto stage = [&](int p) {
#pragma unroll
    for (int i = 0; i < 4; ++i) {
      const unsigned short* g = wp + p * 8192 + (i * 256 + tid) * 8;
      unsigned short* l = &wlds[p & 1][(i * 256 + wave * 64) * 8];  // HW adds lane*16B
      __builtin_amdgcn_global_load_lds(
          (const __attribute__((address_space(1))) void*)g,
          (__attribute__((address_space(3))) void*)l, 16, 0, 0);
    }
  };

  stage(0);  // in flight while we build A-fragments

  // A-fragments: global fp32 -> bf16 regs, held for the whole kernel.
  // A[m = l15][k = quad*8+j] per 16x16x32 K-tile.
  bf16x8 xf[4], hf[4];
  {
    const float* xr = x  + (rb + l15) * 128;
    const float* hr = hp + (rb + l15) * 128;
#pragma unroll
    for (int kt = 0; kt < 4; ++kt) {
      int off = kt * 32 + quad * 8;
      xf[kt] = cvt8(*(const float4*)(xr + off), *(const float4*)(xr + off + 4));
      hf[kt] = cvt8(*(const float4*)(hr + off), *(const float4*)(hr + off + 4));
    }
  }
  float atts[4];
#pragma unroll
  for (int r = 0; r < 4; ++r) atts[r] = att[rb + quad * 4 + r];

  f32x4 acc[4], keep[4];

  // 16 ds_read_b128 + 16 MFMA per phase, wave-linear reads (0 conflicts)
  auto gemm = [&](int b, const bf16x8 (&af)[4]) {
#pragma unroll
    for (int nt = 0; nt < 4; ++nt)
#pragma unroll
      for (int kt = 0; kt < 4; ++kt) {
        bf16x8 bfrag = *(const bf16x8*)&wlds[b][((nt * 4 + kt) * 64 + lane) * 8];
        acc[nt] = __builtin_amdgcn_mfma_f32_16x16x32_bf16(af[kt], bfrag, acc[nt], 0, 0, 0);
      }
  };
  auto fence = [&]() {
    asm volatile("s_waitcnt vmcnt(0)" ::: "memory");
    __syncthreads();
  };

  fence();  // phase-0 weights resident; A-frag loads also drained

#pragma unroll
  for (int ch = 0; ch < 2; ++ch) {
    const int pb = ch * 6;   // phase base; buffer parity for phase pb+m is m&1
    const int cb = ch * 64;  // column base
#pragma unroll
    for (int nt = 0; nt < 4; ++nt) acc[nt] = (f32x4)0.f;

    // pass 0: x.Wx_r
    stage(pb + 1); gemm(0, xf); fence();
    // pass 1: + h.Wh_r -> r
    stage(pb + 2); gemm(1, hf);
#pragma unroll
    for (int nt = 0; nt < 4; ++nt) {
      int col = cb + nt * 16 + l15;
      float br = bx[128 + col] + bh[128 + col];
#pragma unroll
      for (int r = 0; r < 4; ++r) {
        keep[nt][r] = sigmoid_f(acc[nt][r] + br);
        acc[nt][r] = 0.f;
      }
    }
    fence();
    // pass 2: h.Wh_h -> t = r * (g + bh_h)
    stage(pb + 3); gemm(0, hf);
#pragma unroll
    for (int nt = 0; nt < 4; ++nt) {
      int col = cb + nt * 16 + l15;
      float bhh = bh[256 + col];
#pragma unroll
      for (int r = 0; r < 4; ++r) {
        keep[nt][r] = keep[nt][r] * (acc[nt][r] + bhh);
        acc[nt][r] = 0.f;
      }
    }
    fence();
    // pass 3: x.Wx_h -> h_tilde = tanh(g + bx_h + t)
    stage(pb + 4); gemm(1, xf);
#pragma unroll
    for (int nt = 0; nt < 4; ++nt) {
      int col = cb + nt * 16 + l15;
      float bxh = bx[256 + col];
#pragma unroll
      for (int r = 0; r < 4; ++r) {
        keep[nt][r] = tanh_f(acc[nt][r] + bxh + keep[nt][r]);
        acc[nt][r] = 0.f;
      }
    }
    fence();
    // pass 4: x.Wx_u
    stage(pb + 5); gemm(0, xf); fence();
    // pass 5: + h.Wh_u -> u, blend, store this col-half
    if (pb + 6 < 12) stage(pb + 6);
    gemm(1, hf);
#pragma unroll
    for (int nt = 0; nt < 4; ++nt) {
      int col = cb + nt * 16 + l15;
      float bu = bx[col] + bh[col];
#pragma unroll
      for (int r = 0; r < 4; ++r) {
        int row = rb + quad * 4 + r;
        float u  = sigmoid_f(acc[nt][r] + bu);
        float ua = atts[r] * u;
        float h0 = hp[row * 128 + col];
        out[row * 128 + col] = fmaf(ua, keep[nt][r] - h0, h0);  // (1-ua)*h0 + ua*ht
      }
    }
    if (pb + 6 < 12) fence();
  }
}

extern "C" void kernel_launch(void* const* d_in, const int* in_sizes, int n_in,
                              void* d_out, int out_size, void* d_ws, size_t ws_size,
                              hipStream_t stream) {
  const float* x   = (const float*)d_in[0];
  const float* hpv = (const float*)d_in[1];
  const float* att = (const float*)d_in[2];
  const float* Wx  = (const float*)d_in[3];
  const float* bx  = (const float*)d_in[4];
  const float* Wh  = (const float*)d_in[5];
  const float* bh  = (const float*)d_in[6];
  float* out = (float*)d_out;
  unsigned short* wp = (unsigned short*)d_ws;  // 196,608 B of scratch

  pack_weights_kernel<<<48, 256, 0, stream>>>(Wx, Wh, wp);
  augru_kernel<<<1024, 256, 0, stream>>>(x, hpv, att, wp, bx, bh, out);
}